// Round 6
// baseline (161.752 us; speedup 1.0000x reference)
//
#include <hip/hip_runtime.h>
#include <hip/hip_bf16.h>

typedef float f32x4  __attribute__((ext_vector_type(4)));
typedef short bf16x8 __attribute__((ext_vector_type(8)));

__device__ __forceinline__ short bf16r(float x) {
    unsigned u = __builtin_bit_cast(unsigned, x);
    u += 0x7fffu + ((u >> 16) & 1u);
    return (short)(u >> 16);
}

// prepass: head (2M) + dep (2M) f32 -> bf16 into ws
__global__ void cvt_kernel(const float* __restrict__ head, const float* __restrict__ dep,
                           short* __restrict__ hb, short* __restrict__ db) {
    const int n8 = 8 * 512 * 512 / 8;
    int i = blockIdx.x * blockDim.x + threadIdx.x;
    const float* src = (i < n8) ? head : dep;
    short* dst = (i < n8) ? hb : db;
    int j = (i < n8) ? i : i - n8;
    f32x4 a = *(const f32x4*)(src + (size_t)j * 8);
    f32x4 c = *(const f32x4*)(src + (size_t)j * 8 + 4);
    bf16x8 v;
#pragma unroll
    for (int e = 0; e < 4; ++e) { v[e] = bf16r(a[e]); v[4 + e] = bf16r(c[e]); }
    *(bf16x8*)(dst + (size_t)j * 8) = v;
}

// ---- main: 256x256 tile, 8 waves (4m x 2n, wave tile 64x128), BK=64.
// A: direct global->VGPR fragments + in-register U-scale (no LDS for A).
// B: global_load_lds w/ swizzle, double-buffered. One barrier per K-tile.
__global__ __launch_bounds__(512, 2)
void bla_gemm6(const short* __restrict__ headb,
               const short* __restrict__ depb,
               const float* __restrict__ U,
               float* __restrict__ out)
{
    constexpr int S = 512, D = 512, L = 32, BM = 256, BN = 256, BK = 64, NT = 8;

    __shared__ __align__(16) short Bl[2][BN * BK];   // 2 x 32KB = 64KB

    const int tid = threadIdx.x, lane = tid & 63, wid = tid >> 6;
    const int wm = wid >> 1, wn = wid & 1;           // 4m x 2n waves, wave 64x128

    // XCD swizzle: 1024 blocks, 128/XCD = one b per XCD; it outer, l inner.
    const int swz = (blockIdx.x & 7) * ((int)gridDim.x >> 3) + (blockIdx.x >> 3);
    const int b = swz >> 7, rem = swz & 127;
    const int it = rem >> 6, l = (rem >> 1) & 31, ot = rem & 1;
    const int i0 = it * BM, o0 = ot * BN;

    // A fragment base: row = i0 + wm*64 + mf*16 + (lane&15); k-slice (lane>>4)*8
    const short* hfrag = headb + (size_t)(b * S + i0 + wm * 64 + (lane & 15)) * D
                         + ((lane >> 4) * 8);
    const float* ubase = U + (size_t)l * D + ((lane >> 4) * 8);

    // B staging: linear LDS dest, inverse-swizzled global source (rule #21)
    const int bso = ((lane & 7) * 16) ^ ((lane >> 3) << 4);
    const short* dbase = depb + (size_t)(b * S + o0) * D;

    bf16x8 rw[2][4];     // raw A frags for next tile [ks][mf]
    bf16x8 sc[2][4];     // scaled A frags for current tile [ks][mf]
    f32x4  uf[2][2];     // U values for next tile [ks][half]
    bf16x8 bfr[8];
    f32x4  acc[4][8] = {};

#define SB()  __builtin_amdgcn_sched_barrier(0)
#define BAR() __builtin_amdgcn_s_barrier()

#define B_ISSUE(tt) do {                                                        \
        _Pragma("unroll")                                                       \
        for (int q = 0; q < 4; ++q) {                                           \
            const int rg = wid * 32 + q * 8 + (lane >> 3);                      \
            const char* s_ = (const char*)dbase +                               \
                ((size_t)rg * D + (size_t)(tt) * BK) * 2 + bso;                 \
            __builtin_amdgcn_global_load_lds(                                   \
                (const __attribute__((address_space(1))) void*)s_,              \
                (__attribute__((address_space(3))) void*)&Bl[(tt) & 1][(wid * 32 + q * 8) * BK], \
                16, 0, 0);                                                      \
        }                                                                       \
    } while (0)

#define AQ_ISSUE(tt, ks) do {                                                   \
        _Pragma("unroll")                                                       \
        for (int mf = 0; mf < 4; ++mf)                                          \
            rw[ks][mf] = *(const bf16x8*)(hfrag + (size_t)(mf * 16) * D +       \
                                          (tt) * BK + (ks) * 32);               \
    } while (0)

#define U_ISSUE(tt) do {                                                        \
        _Pragma("unroll")                                                       \
        for (int ks = 0; ks < 2; ++ks)                                          \
            _Pragma("unroll")                                                   \
            for (int h = 0; h < 2; ++h)                                         \
                uf[ks][h] = *(const f32x4*)(ubase + (tt) * BK + ks * 32 + h * 4);\
    } while (0)

    // scale raw->sc (consumes rw, uf; compiler auto-waits vmcnt)
#define SCALE_ALL() do {                                                        \
        _Pragma("unroll")                                                       \
        for (int ks = 0; ks < 2; ++ks)                                          \
            _Pragma("unroll")                                                   \
            for (int mf = 0; mf < 4; ++mf) {                                    \
                bf16x8 av;                                                      \
                _Pragma("unroll")                                               \
                for (int e = 0; e < 8; ++e) {                                   \
                    float f = __builtin_bit_cast(float,                         \
                        (unsigned)((unsigned short)rw[ks][mf][e]) << 16)        \
                        * uf[ks][e >> 2][e & 3];                                \
                    av[e] = __builtin_bit_cast(short, __float2bfloat16(f));     \
                }                                                               \
                sc[ks][mf] = av;                                                \
            }                                                                   \
    } while (0)

#define DSREAD_B(buf_, ks_) do {                                                \
        const int cb = (ks_) * 64 + ((lane >> 4) << 4);                         \
        _Pragma("unroll")                                                       \
        for (int f = 0; f < 8; ++f) {                                           \
            const int row = wn * 128 + f * 16 + (lane & 15);                    \
            bfr[f] = *(const bf16x8*)&Bl[buf_][row * BK + ((cb ^ ((row & 7) << 4)) >> 1)]; \
        }                                                                       \
    } while (0)

    // 32 MFMA: all 4 m-frags x 8 n-frags for one ks
#define MFMA32(ks_) do {                                                        \
        __builtin_amdgcn_s_setprio(1);                                          \
        _Pragma("unroll")                                                       \
        for (int m = 0; m < 4; ++m)                                             \
            _Pragma("unroll")                                                   \
            for (int n = 0; n < 8; ++n)                                         \
                acc[m][n] = __builtin_amdgcn_mfma_f32_16x16x32_bf16(            \
                    sc[ks_][m], bfr[n], acc[m][n], 0, 0, 0);                    \
        __builtin_amdgcn_s_setprio(0);                                          \
    } while (0)

    // ---- prologue: stage tile 0
    B_ISSUE(0);
    AQ_ISSUE(0, 0); AQ_ISSUE(0, 1); U_ISSUE(0);
    SB();
    SCALE_ALL();          // auto-waits rw(0); drains B(0) too (B is older)
    SB();
    asm volatile("s_waitcnt vmcnt(0)" ::: "memory");  // own B(0) landed
    SB();
    BAR();

#pragma unroll
    for (int t = 0; t < NT; ++t) {
        const int c = t & 1;

        // issue next tile's B gloads first (oldest), then A ks0 frags
        if (t + 1 < NT) { B_ISSUE(t + 1); AQ_ISSUE(t + 1, 0); }
        SB();
        DSREAD_B(c, 0);
        SB();
        MFMA32(0);
        SB();
        // mid-tile: next tile's U + A ks1 frags
        if (t + 1 < NT) { U_ISSUE(t + 1); AQ_ISSUE(t + 1, 1); }
        SB();
        DSREAD_B(c, 1);
        SB();
        MFMA32(1);
        SB();
        if (t + 1 < NT) {
            SCALE_ALL();   // scale next tile's A (raw aged >=1 phase; L2 hits)
            SB();
            // own B(t+1) gloads complete before crossing the barrier (all
            // outstanding vmem is >=600cyc aged here -> effectively free)
            asm volatile("s_waitcnt vmcnt(0)" ::: "memory");
            SB();
            BAR();
        }
    }

    // ---- epilogue: C/D layout col=lane&15, row=(lane>>4)*4+r
    float* op = out + (size_t)(b * L + l) * S * S;
#pragma unroll
    for (int m = 0; m < 4; ++m) {
        const int row0 = i0 + wm * 64 + m * 16 + ((lane >> 4) << 2);
#pragma unroll
        for (int n = 0; n < 8; ++n) {
            const int col = o0 + wn * 128 + n * 16 + (lane & 15);
#pragma unroll
            for (int r = 0; r < 4; ++r)
                op[(size_t)(row0 + r) * S + col] = acc[m][n][r];
        }
    }

#undef SB
#undef BAR
#undef B_ISSUE
#undef AQ_ISSUE
#undef U_ISSUE
#undef SCALE_ALL
#undef DSREAD_B
#undef MFMA32
}

// ---------------- fallback (proven R1 kernel): used only if ws < 8MB ----------
__global__ __launch_bounds__(256, 2)
void bla_fb(const float* __restrict__ head, const float* __restrict__ dep,
            const float* __restrict__ U, float* __restrict__ out)
{
    constexpr int S = 512, D = 512, L = 32, BM = 128, BN = 128, BK = 64, NT = 8;
    __shared__ short Al[2][BM * BK];
    __shared__ short Bl[2][BN * BK];
    const int tid = threadIdx.x, lane = tid & 63, wid = tid >> 6;
    const int wm = wid >> 1, wn = wid & 1;
    const int swz = (blockIdx.x & 7) * ((int)gridDim.x >> 3) + (blockIdx.x >> 3);
    const int b = swz >> 9, rem = swz & 511;
    const int l = rem >> 4, it = (rem >> 2) & 3, ot = rem & 3;
    const int i0 = it * BM, o0 = ot * BN;
    const int srow = tid >> 3, scol = (tid & 7) * 8, swb = scol * 2;
    const float* hb = head + (size_t)(b * S + i0 + srow) * D + scol;
    const float* db = dep + (size_t)(b * S + o0 + srow) * D + scol;
    const float* ub = U + l * D + scol;
    f32x4 ra[4][2], rb[4][2], ru[2];
#define FSTAGE_LOAD(t) do { const int k0_ = (t) * BK;                              \
        ru[0] = *(const f32x4*)(ub + k0_); ru[1] = *(const f32x4*)(ub + k0_ + 4);  \
        _Pragma("unroll") for (int p_ = 0; p_ < 4; ++p_) {                         \
            ra[p_][0] = *(const f32x4*)(hb + k0_ + p_ * 32 * D);                   \
            ra[p_][1] = *(const f32x4*)(hb + k0_ + p_ * 32 * D + 4);               \
            rb[p_][0] = *(const f32x4*)(db + k0_ + p_ * 32 * D);                   \
            rb[p_][1] = *(const f32x4*)(db + k0_ + p_ * 32 * D + 4); } } while (0)
#define FSTAGE_WRITE(buf) do { _Pragma("unroll") for (int p_ = 0; p_ < 4; ++p_) {  \
            const int row_ = srow + p_ * 32; const int sb_ = swb ^ ((row_ & 7) << 4); \
            bf16x8 av_, bv_;                                                       \
            _Pragma("unroll") for (int q_ = 0; q_ < 2; ++q_)                       \
                _Pragma("unroll") for (int j_ = 0; j_ < 4; ++j_) {                 \
                    av_[q_ * 4 + j_] = bf16r(ra[p_][q_][j_] * ru[q_][j_]);         \
                    bv_[q_ * 4 + j_] = bf16r(rb[p_][q_][j_]); }                    \
            *(bf16x8*)&Al[buf][row_ * BK + (sb_ >> 1)] = av_;                      \
            *(bf16x8*)&Bl[buf][row_ * BK + (sb_ >> 1)] = bv_; } } while (0)
    f32x4 acc[4][4] = {};
    const int cbase = (lane >> 4) << 4, rsw = (lane & 7) << 4;
#define FCOMPUTE(buf) do { _Pragma("unroll") for (int ks_ = 0; ks_ < 2; ++ks_) {   \
            const int sb2_ = (ks_ * 64 + cbase) ^ rsw; bf16x8 af_[4], bfr_[4];     \
            _Pragma("unroll") for (int f_ = 0; f_ < 4; ++f_) {                     \
                af_[f_] = *(const bf16x8*)&Al[buf][(wm * 64 + f_ * 16 + (lane & 15)) * BK + (sb2_ >> 1)]; \
                bfr_[f_] = *(const bf16x8*)&Bl[buf][(wn * 64 + f_ * 16 + (lane & 15)) * BK + (sb2_ >> 1)]; } \
            _Pragma("unroll") for (int fm_ = 0; fm_ < 4; ++fm_)                    \
                _Pragma("unroll") for (int fn_ = 0; fn_ < 4; ++fn_)                \
                    acc[fm_][fn_] = __builtin_amdgcn_mfma_f32_16x16x32_bf16(       \
                        af_[fm_], bfr_[fn_], acc[fm_][fn_], 0, 0, 0); } } while (0)
    FSTAGE_LOAD(0); FSTAGE_WRITE(0); __syncthreads();
    int cur = 0;
#pragma unroll
    for (int t = 0; t < NT; ++t) {
        if (t + 1 < NT) FSTAGE_LOAD(t + 1);
        FCOMPUTE(cur);
        if (t + 1 < NT) FSTAGE_WRITE(cur ^ 1);
        __syncthreads();
        cur ^= 1;
    }
    float* op = out + (size_t)(b * L + l) * S * S;
#pragma unroll
    for (int fm = 0; fm < 4; ++fm) {
        const int row0 = i0 + wm * 64 + fm * 16 + ((lane >> 4) << 2);
#pragma unroll
        for (int fn = 0; fn < 4; ++fn) {
            const int col = o0 + wn * 64 + fn * 16 + (lane & 15);
#pragma unroll
            for (int r = 0; r < 4; ++r)
                op[(size_t)(row0 + r) * S + col] = acc[fm][fn][r];
        }
    }
#undef FSTAGE_LOAD
#undef FSTAGE_WRITE
#undef FCOMPUTE
}

extern "C" void kernel_launch(void* const* d_in, const int* in_sizes, int n_in,
                              void* d_out, int out_size, void* d_ws, size_t ws_size,
                              hipStream_t stream)
{
    const float* head = (const float*)d_in[0];
    const float* dep  = (const float*)d_in[1];
    const float* U    = (const float*)d_in[2];
    float* out        = (float*)d_out;

    const size_t nelem = (size_t)8 * 512 * 512;
    const size_t need  = nelem * 2 * 2;   // 8MB
    if (ws_size >= need) {
        short* headb = (short*)d_ws;
        short* depb  = headb + nelem;
        cvt_kernel<<<dim3(2048), dim3(256), 0, stream>>>(head, dep, headb, depb);
        bla_gemm6<<<dim3(1024), dim3(512), 0, stream>>>(headb, depb, U, out);
    } else {
        bla_fb<<<dim3(4096), dim3(256), 0, stream>>>(head, dep, U, out);
    }
}

// Round 7
// 140.734 us; speedup vs baseline: 1.1493x; 1.1493x over previous
//
#include <hip/hip_runtime.h>
#include <hip/hip_bf16.h>

typedef float f32x4  __attribute__((ext_vector_type(4)));
typedef short bf16x8 __attribute__((ext_vector_type(8)));

__device__ __forceinline__ short bf16r(float x) {
    unsigned u = __builtin_bit_cast(unsigned, x);
    u += 0x7fffu + ((u >> 16) & 1u);
    return (short)(u >> 16);
}

// prepass: head (2M) + dep (2M) f32 -> bf16 into ws
__global__ void cvt_kernel(const float* __restrict__ head, const float* __restrict__ dep,
                           short* __restrict__ hb, short* __restrict__ db) {
    const int n8 = 8 * 512 * 512 / 8;
    int i = blockIdx.x * blockDim.x + threadIdx.x;
    const float* src = (i < n8) ? head : dep;
    short* dst = (i < n8) ? hb : db;
    int j = (i < n8) ? i : i - n8;
    f32x4 a = *(const f32x4*)(src + (size_t)j * 8);
    f32x4 c = *(const f32x4*)(src + (size_t)j * 8 + 4);
    bf16x8 v;
#pragma unroll
    for (int e = 0; e < 4; ++e) { v[e] = bf16r(a[e]); v[4 + e] = bf16r(c[e]); }
    *(bf16x8*)(dst + (size_t)j * 8) = v;
}

// ---- main: 256x128 tile x 2 l-values per block, 8 waves (4m x 2n, wave 64x64).
// A (raw head) and B (dep) both staged via global_load_lds (zero staging VALU);
// U-scale applied in-register per l between LDS read and MFMA.
// LDS: A 2x32KB + B 2x16KB + U 4KB = 100KB -> 1 block/CU, 2 waves/SIMD.
__global__ __launch_bounds__(512, 2)
void bla_gemm7(const short* __restrict__ headb,
               const short* __restrict__ depb,
               const float* __restrict__ U,
               float* __restrict__ out)
{
    constexpr int S = 512, D = 512, L = 32, BM = 256, BN = 128, BK = 64, NT = 8;

    __shared__ __align__(16) short Al[2][BM * BK];   // 32KB each
    __shared__ __align__(16) short Bl[2][BN * BK];   // 16KB each
    __shared__ __align__(16) float Ul[2][512];       // 4KB: U rows l0, l0+1

    const int tid = threadIdx.x, lane = tid & 63, wid = tid >> 6;
    const int wm = wid >> 1, wn = wid & 1;           // 4m x 2n, wave tile 64x64

    // XCD swizzle: 1024 blocks, 128/XCD = one b per XCD.
    // Within XCD: it|ot outer, lp inner -> head/dep panels L2-hot across 16 lp.
    const int swz = (blockIdx.x & 7) * ((int)gridDim.x >> 3) + (blockIdx.x >> 3);
    const int b = swz >> 7, rem = swz & 127;
    const int it = rem >> 6, ot = (rem >> 4) & 3, lp = rem & 15;
    const int i0 = it * BM, o0 = ot * BN, l0 = lp * 2;

    // gload_lds: linear LDS dest, inverse-swizzled global source (rule #21)
    const int bso = ((lane & 7) * 16) ^ ((lane >> 3) << 4);
    const char* asrc = (const char*)(headb + (size_t)(b * S + i0) * D) + bso;
    const char* bsrc = (const char*)(depb + (size_t)(b * S + o0) * D) + bso;

#define SB()  __builtin_amdgcn_sched_barrier(0)
#define BAR() __builtin_amdgcn_s_barrier()

    // 4 gload_lds/wave: 256-row A tile (raw head, no scale)
#define A_ISSUE(tt) do {                                                        \
        _Pragma("unroll")                                                       \
        for (int q = 0; q < 4; ++q) {                                           \
            const int rg = wid * 32 + q * 8 + (lane >> 3);                      \
            __builtin_amdgcn_global_load_lds(                                   \
                (const __attribute__((address_space(1))) void*)(asrc +          \
                    ((size_t)rg * D + (size_t)(tt) * BK) * 2),                  \
                (__attribute__((address_space(3))) void*)                       \
                    (&Al[(tt) & 1][(wid * 32 + q * 8) * BK] + lane * 8),        \
                16, 0, 0);                                                      \
        }                                                                       \
    } while (0)

    // 2 gload_lds/wave: 128-row B tile
#define B_ISSUE(tt) do {                                                        \
        _Pragma("unroll")                                                       \
        for (int q = 0; q < 2; ++q) {                                           \
            const int rg = wid * 16 + q * 8 + (lane >> 3);                      \
            __builtin_amdgcn_global_load_lds(                                   \
                (const __attribute__((address_space(1))) void*)(bsrc +          \
                    ((size_t)rg * D + (size_t)(tt) * BK) * 2),                  \
                (__attribute__((address_space(3))) void*)                       \
                    (&Bl[(tt) & 1][(wid * 16 + q * 8) * BK] + lane * 8),        \
                16, 0, 0);                                                      \
        }                                                                       \
    } while (0)

    f32x4 acc0[4][4] = {}, acc1[4][4] = {};   // per-l accumulators
    bf16x8 af[4], bfr[4], av[4];
    f32x4 uf[2][2][2];                        // [ks][li][half]

#define DSREAD_A(buf_, ks_) do {                                                \
        const int cb = (ks_) * 64 + ((lane >> 4) << 4);                         \
        _Pragma("unroll")                                                       \
        for (int f = 0; f < 4; ++f) {                                           \
            const int row = wm * 64 + f * 16 + (lane & 15);                     \
            af[f] = *(const bf16x8*)&Al[buf_][row * BK + ((cb ^ ((row & 7) << 4)) >> 1)]; \
        }                                                                       \
    } while (0)

#define DSREAD_B(buf_, ks_) do {                                                \
        const int cb = (ks_) * 64 + ((lane >> 4) << 4);                         \
        _Pragma("unroll")                                                       \
        for (int f = 0; f < 4; ++f) {                                           \
            const int row = wn * 64 + f * 16 + (lane & 15);                     \
            bfr[f] = *(const bf16x8*)&Bl[buf_][row * BK + ((cb ^ ((row & 7) << 4)) >> 1)]; \
        }                                                                       \
    } while (0)

    // U slices for tile tt from LDS: elem k = tt*64 + ks*32 + (lane>>4)*8 + e
#define UF_READ(tt) do {                                                        \
        _Pragma("unroll")                                                       \
        for (int ks = 0; ks < 2; ++ks)                                          \
            _Pragma("unroll")                                                   \
            for (int li = 0; li < 2; ++li)                                      \
                _Pragma("unroll")                                               \
                for (int h = 0; h < 2; ++h)                                     \
                    uf[ks][li][h] = *(const f32x4*)&Ul[li][(tt) * 64 + ks * 32  \
                        + ((lane >> 4) << 3) + h * 4];                          \
    } while (0)

    // scale raw A frags by U[l0+li] slice ks -> av
#define SCALE(li_, ks_) do {                                                    \
        _Pragma("unroll")                                                       \
        for (int mf = 0; mf < 4; ++mf) {                                        \
            bf16x8 t_;                                                          \
            _Pragma("unroll")                                                   \
            for (int e = 0; e < 8; ++e) {                                       \
                float f = __builtin_bit_cast(float,                             \
                    (unsigned)((unsigned short)af[mf][e]) << 16)                \
                    * uf[ks_][li_][e >> 2][e & 3];                              \
                t_[e] = __builtin_bit_cast(short, __float2bfloat16(f));         \
            }                                                                   \
            av[mf] = t_;                                                        \
        }                                                                       \
    } while (0)

#define MFMA16(accX) do {                                                       \
        __builtin_amdgcn_s_setprio(1);                                          \
        _Pragma("unroll")                                                       \
        for (int m = 0; m < 4; ++m)                                             \
            _Pragma("unroll")                                                   \
            for (int n = 0; n < 4; ++n)                                         \
                accX[m][n] = __builtin_amdgcn_mfma_f32_16x16x32_bf16(           \
                    av[m], bfr[n], accX[m][n], 0, 0, 0);                        \
        __builtin_amdgcn_s_setprio(0);                                          \
    } while (0)

    // ---- prologue: stage U rows to LDS; stage tile 0; single full drain
    if (tid < 256) {
        const int li = tid >> 7, idx = (tid & 127) * 4;
        *(f32x4*)&Ul[li][idx] = *(const f32x4*)&U[(size_t)(l0 + li) * D + idx];
    }
    B_ISSUE(0);
    A_ISSUE(0);
    SB();
    asm volatile("s_waitcnt vmcnt(0) lgkmcnt(0)" ::: "memory");
    SB();
    BAR();

#pragma unroll
    for (int t = 0; t < NT; ++t) {
        const int c = t & 1;

        // reads for ks0 + this tile's U; issue next tile's staging (aged drain later)
        UF_READ(t);
        DSREAD_A(c, 0); DSREAD_B(c, 0);
        if (t + 1 < NT) { B_ISSUE(t + 1); A_ISSUE(t + 1); }
        SB();
        SCALE(0, 0); MFMA16(acc0);
        SCALE(1, 0); MFMA16(acc1);
        SB();
        DSREAD_A(c, 1); DSREAD_B(c, 1);
        SB();
        SCALE(0, 1); MFMA16(acc0);
        SCALE(1, 1); MFMA16(acc1);
        SB();
        if (t + 1 < NT) {
            // gloads into buf c^1 were issued ~64 MFMAs ago -> aged, free drain
            asm volatile("s_waitcnt vmcnt(0)" ::: "memory");
            SB();
            BAR();
        }
    }

    // ---- epilogue: C/D layout col=lane&15, row=(lane>>4)*4+r; 2 l-planes
#pragma unroll
    for (int li = 0; li < 2; ++li) {
        float* op = out + (size_t)(b * L + l0 + li) * S * S;
#pragma unroll
        for (int m = 0; m < 4; ++m) {
            const int row0 = i0 + wm * 64 + m * 16 + ((lane >> 4) << 2);
#pragma unroll
            for (int n = 0; n < 4; ++n) {
                const int col = o0 + wn * 64 + n * 16 + (lane & 15);
#pragma unroll
                for (int r = 0; r < 4; ++r)
                    op[(size_t)(row0 + r) * S + col] =
                        li ? acc1[m][n][r] : acc0[m][n][r];
            }
        }
    }

#undef SB
#undef BAR
#undef A_ISSUE
#undef B_ISSUE
#undef DSREAD_A
#undef DSREAD_B
#undef UF_READ
#undef SCALE
#undef MFMA16
}

// ---------------- fallback (proven R1 kernel): used only if ws < 8MB ----------
__global__ __launch_bounds__(256, 2)
void bla_fb(const float* __restrict__ head, const float* __restrict__ dep,
            const float* __restrict__ U, float* __restrict__ out)
{
    constexpr int S = 512, D = 512, L = 32, BM = 128, BN = 128, BK = 64, NT = 8;
    __shared__ short Al[2][BM * BK];
    __shared__ short Bl[2][BN * BK];
    const int tid = threadIdx.x, lane = tid & 63, wid = tid >> 6;
    const int wm = wid >> 1, wn = wid & 1;
    const int swz = (blockIdx.x & 7) * ((int)gridDim.x >> 3) + (blockIdx.x >> 3);
    const int b = swz >> 9, rem = swz & 511;
    const int l = rem >> 4, it = (rem >> 2) & 3, ot = rem & 3;
    const int i0 = it * BM, o0 = ot * BN;
    const int srow = tid >> 3, scol = (tid & 7) * 8, swb = scol * 2;
    const float* hb = head + (size_t)(b * S + i0 + srow) * D + scol;
    const float* db = dep + (size_t)(b * S + o0 + srow) * D + scol;
    const float* ub = U + l * D + scol;
    f32x4 ra[4][2], rb[4][2], ru[2];
#define FSTAGE_LOAD(t) do { const int k0_ = (t) * BK;                              \
        ru[0] = *(const f32x4*)(ub + k0_); ru[1] = *(const f32x4*)(ub + k0_ + 4);  \
        _Pragma("unroll") for (int p_ = 0; p_ < 4; ++p_) {                         \
            ra[p_][0] = *(const f32x4*)(hb + k0_ + p_ * 32 * D);                   \
            ra[p_][1] = *(const f32x4*)(hb + k0_ + p_ * 32 * D + 4);               \
            rb[p_][0] = *(const f32x4*)(db + k0_ + p_ * 32 * D);                   \
            rb[p_][1] = *(const f32x4*)(db + k0_ + p_ * 32 * D + 4); } } while (0)
#define FSTAGE_WRITE(buf) do { _Pragma("unroll") for (int p_ = 0; p_ < 4; ++p_) {  \
            const int row_ = srow + p_ * 32; const int sb_ = swb ^ ((row_ & 7) << 4); \
            bf16x8 av_, bv_;                                                       \
            _Pragma("unroll") for (int q_ = 0; q_ < 2; ++q_)                       \
                _Pragma("unroll") for (int j_ = 0; j_ < 4; ++j_) {                 \
                    av_[q_ * 4 + j_] = bf16r(ra[p_][q_][j_] * ru[q_][j_]);         \
                    bv_[q_ * 4 + j_] = bf16r(rb[p_][q_][j_]); }                    \
            *(bf16x8*)&Al[buf][row_ * BK + (sb_ >> 1)] = av_;                      \
            *(bf16x8*)&Bl[buf][row_ * BK + (sb_ >> 1)] = bv_; } } while (0)
    f32x4 acc[4][4] = {};
    const int cbase = (lane >> 4) << 4, rsw = (lane & 7) << 4;
#define FCOMPUTE(buf) do { _Pragma("unroll") for (int ks_ = 0; ks_ < 2; ++ks_) {   \
            const int sb2_ = (ks_ * 64 + cbase) ^ rsw; bf16x8 af_[4], bfr_[4];     \
            _Pragma("unroll") for (int f_ = 0; f_ < 4; ++f_) {                     \
                af_[f_] = *(const bf16x8*)&Al[buf][(wm * 64 + f_ * 16 + (lane & 15)) * BK + (sb2_ >> 1)]; \
                bfr_[f_] = *(const bf16x8*)&Bl[buf][(wn * 64 + f_ * 16 + (lane & 15)) * BK + (sb2_ >> 1)]; } \
            _Pragma("unroll") for (int fm_ = 0; fm_ < 4; ++fm_)                    \
                _Pragma("unroll") for (int fn_ = 0; fn_ < 4; ++fn_)                \
                    acc[fm_][fn_] = __builtin_amdgcn_mfma_f32_16x16x32_bf16(       \
                        af_[fm_], bfr_[fn_], acc[fm_][fn_], 0, 0, 0); } } while (0)
    FSTAGE_LOAD(0); FSTAGE_WRITE(0); __syncthreads();
    int cur = 0;
#pragma unroll
    for (int t = 0; t < NT; ++t) {
        if (t + 1 < NT) FSTAGE_LOAD(t + 1);
        FCOMPUTE(cur);
        if (t + 1 < NT) FSTAGE_WRITE(cur ^ 1);
        __syncthreads();
        cur ^= 1;
    }
    float* op = out + (size_t)(b * L + l) * S * S;
#pragma unroll
    for (int fm = 0; fm < 4; ++fm) {
        const int row0 = i0 + wm * 64 + fm * 16 + ((lane >> 4) << 2);
#pragma unroll
        for (int fn = 0; fn < 4; ++fn) {
            const int col = o0 + wn * 64 + fn * 16 + (lane & 15);
#pragma unroll
            for (int r = 0; r < 4; ++r)
                op[(size_t)(row0 + r) * S + col] = acc[fm][fn][r];
        }
    }
#undef FSTAGE_LOAD
#undef FSTAGE_WRITE
#undef FCOMPUTE
}

extern "C" void kernel_launch(void* const* d_in, const int* in_sizes, int n_in,
                              void* d_out, int out_size, void* d_ws, size_t ws_size,
                              hipStream_t stream)
{
    const float* head = (const float*)d_in[0];
    const float* dep  = (const float*)d_in[1];
    const float* U    = (const float*)d_in[2];
    float* out        = (float*)d_out;

    const size_t nelem = (size_t)8 * 512 * 512;
    const size_t need  = nelem * 2 * 2;   // 8MB
    if (ws_size >= need) {
        short* headb = (short*)d_ws;
        short* depb  = headb + nelem;
        cvt_kernel<<<dim3(2048), dim3(256), 0, stream>>>(head, dep, headb, depb);
        bla_gemm7<<<dim3(1024), dim3(512), 0, stream>>>(headb, depb, U, out);
    } else {
        bla_fb<<<dim3(4096), dim3(256), 0, stream>>>(head, dep, U, out);
    }
}

// Round 8
// 112.903 us; speedup vs baseline: 1.4327x; 1.2465x over previous
//
#include <hip/hip_runtime.h>
#include <hip/hip_bf16.h>

typedef float f32x4  __attribute__((ext_vector_type(4)));
typedef short bf16x8 __attribute__((ext_vector_type(8)));

__device__ __forceinline__ short bf16r(float x) {
    unsigned u = __builtin_bit_cast(unsigned, x);
    u += 0x7fffu + ((u >> 16) & 1u);
    return (short)(u >> 16);
}

// prepass: head (2M) + dep (2M) f32 -> bf16 into ws
__global__ void cvt_kernel(const float* __restrict__ head, const float* __restrict__ dep,
                           short* __restrict__ hb, short* __restrict__ db) {
    const int n8 = 8 * 512 * 512 / 8;
    int i = blockIdx.x * blockDim.x + threadIdx.x;
    const float* src = (i < n8) ? head : dep;
    short* dst = (i < n8) ? hb : db;
    int j = (i < n8) ? i : i - n8;
    f32x4 a = *(const f32x4*)(src + (size_t)j * 8);
    f32x4 c = *(const f32x4*)(src + (size_t)j * 8 + 4);
    bf16x8 v;
#pragma unroll
    for (int e = 0; e < 4; ++e) { v[e] = bf16r(a[e]); v[4 + e] = bf16r(c[e]); }
    *(bf16x8*)(dst + (size_t)j * 8) = v;
}

// ---- main: 128x128 tile x 2 l-values, 4 waves (2m x 2n, wave 64x64), BK=64.
// A and B both staged RAW via global_load_lds (zero staging VALU/regs).
// U-scale applied on-read, amortized over 2 l's (A-frags+B-frags read once).
// LDS: A 2x16KB + B 2x16KB + U 4KB = 68KB -> 2 blocks/CU (desync overlap).
// One barrier + one aged vmcnt per K-tile.
__global__ __launch_bounds__(256, 2)
void bla_gemm8(const short* __restrict__ headb,
               const short* __restrict__ depb,
               const float* __restrict__ U,
               float* __restrict__ out)
{
    constexpr int S = 512, D = 512, L = 32, BM = 128, BN = 128, BK = 64, NT = 8;

    __shared__ __align__(16) short Al[2][BM * BK];   // 16KB each
    __shared__ __align__(16) short Bl[2][BN * BK];   // 16KB each
    __shared__ __align__(16) float Ul[2][512];       // 4KB

    const int tid = threadIdx.x, lane = tid & 63, wid = tid >> 6;
    const int wm = wid >> 1, wn = wid & 1;           // 2m x 2n, wave tile 64x64

    // XCD swizzle: 2048 blocks -> 256/XCD = one b per XCD.
    // Within XCD: it outer (A-panel L2-hot), then ot, lp inner.
    const int swz = (blockIdx.x & 7) * ((int)gridDim.x >> 3) + (blockIdx.x >> 3);
    const int b = swz >> 8, rem = swz & 255;
    const int it = rem >> 6, ot = (rem >> 4) & 3, lp = rem & 15;
    const int i0 = it * BM, o0 = ot * BN, l0 = lp * 2;

    // gload_lds: linear LDS dest, inverse-swizzled global source (rule #21)
    const int bso = ((lane & 7) * 16) ^ ((lane >> 3) << 4);
    const char* asrc = (const char*)(headb + (size_t)(b * S + i0) * D) + bso;
    const char* bsrc = (const char*)(depb + (size_t)(b * S + o0) * D) + bso;

#define SB()  __builtin_amdgcn_sched_barrier(0)
#define BAR() __builtin_amdgcn_s_barrier()

    // 4 gload_lds/wave each: 128-row tile (4 waves x 4 chunks x 8 rows = 128)
#define A_GLOAD(tt) do {                                                        \
        _Pragma("unroll")                                                       \
        for (int q = 0; q < 4; ++q) {                                           \
            const int rg = wid * 32 + q * 8 + (lane >> 3);                      \
            __builtin_amdgcn_global_load_lds(                                   \
                (const __attribute__((address_space(1))) void*)(asrc +          \
                    ((size_t)rg * D + (size_t)(tt) * BK) * 2),                  \
                (__attribute__((address_space(3))) void*)                       \
                    (&Al[(tt) & 1][(wid * 32 + q * 8) * BK] + lane * 8),        \
                16, 0, 0);                                                      \
        }                                                                       \
    } while (0)

#define B_GLOAD(tt) do {                                                        \
        _Pragma("unroll")                                                       \
        for (int q = 0; q < 4; ++q) {                                           \
            const int rg = wid * 32 + q * 8 + (lane >> 3);                      \
            __builtin_amdgcn_global_load_lds(                                   \
                (const __attribute__((address_space(1))) void*)(bsrc +          \
                    ((size_t)rg * D + (size_t)(tt) * BK) * 2),                  \
                (__attribute__((address_space(3))) void*)                       \
                    (&Bl[(tt) & 1][(wid * 32 + q * 8) * BK] + lane * 8),        \
                16, 0, 0);                                                      \
        }                                                                       \
    } while (0)

    f32x4 acc0[4][4] = {}, acc1[4][4] = {};   // 2 l-planes, 64 regs each
    bf16x8 af[4], bfr[4], av[4];
    f32x4 uf[2][2][2];                        // [li][ks][half] for current tile

#define DSREAD_A(buf_, ks_) do {                                                \
        const int cb = (ks_) * 64 + ((lane >> 4) << 4);                         \
        _Pragma("unroll")                                                       \
        for (int f = 0; f < 4; ++f) {                                           \
            const int row = wm * 64 + f * 16 + (lane & 15);                     \
            af[f] = *(const bf16x8*)&Al[buf_][row * BK + ((cb ^ ((row & 7) << 4)) >> 1)]; \
        }                                                                       \
    } while (0)

#define DSREAD_B(buf_, ks_) do {                                                \
        const int cb = (ks_) * 64 + ((lane >> 4) << 4);                         \
        _Pragma("unroll")                                                       \
        for (int f = 0; f < 4; ++f) {                                           \
            const int row = wn * 64 + f * 16 + (lane & 15);                     \
            bfr[f] = *(const bf16x8*)&Bl[buf_][row * BK + ((cb ^ ((row & 7) << 4)) >> 1)]; \
        }                                                                       \
    } while (0)

    // U slices for tile tt (broadcast ds_reads: same addr within 16-lane group)
#define UF_READ(tt) do {                                                        \
        _Pragma("unroll")                                                       \
        for (int li = 0; li < 2; ++li)                                          \
            _Pragma("unroll")                                                   \
            for (int ks = 0; ks < 2; ++ks)                                      \
                _Pragma("unroll")                                               \
                for (int h = 0; h < 2; ++h)                                     \
                    uf[li][ks][h] = *(const f32x4*)&Ul[li][(tt) * 64 + ks * 32  \
                        + ((lane >> 4) << 3) + h * 4];                          \
    } while (0)

    // scale raw A frags by U[l0+li] slice ks -> av
#define SCALE(li_, ks_) do {                                                    \
        _Pragma("unroll")                                                       \
        for (int mf = 0; mf < 4; ++mf) {                                        \
            bf16x8 t_;                                                          \
            _Pragma("unroll")                                                   \
            for (int e = 0; e < 8; ++e) {                                       \
                float f = __builtin_bit_cast(float,                             \
                    (unsigned)((unsigned short)af[mf][e]) << 16)                \
                    * uf[li_][ks_][e >> 2][e & 3];                              \
                t_[e] = __builtin_bit_cast(short, __float2bfloat16(f));         \
            }                                                                   \
            av[mf] = t_;                                                        \
        }                                                                       \
    } while (0)

#define MFMA16(accX) do {                                                       \
        __builtin_amdgcn_s_setprio(1);                                          \
        _Pragma("unroll")                                                       \
        for (int m = 0; m < 4; ++m)                                             \
            _Pragma("unroll")                                                   \
            for (int n = 0; n < 4; ++n)                                         \
                accX[m][n] = __builtin_amdgcn_mfma_f32_16x16x32_bf16(           \
                    av[m], bfr[n], accX[m][n], 0, 0, 0);                        \
        __builtin_amdgcn_s_setprio(0);                                          \
    } while (0)

    // ---- prologue: U rows to LDS; stage tile 0; full drain once
    {
        const int li = tid >> 7, idx = (tid & 127) * 4;
        *(f32x4*)&Ul[li][idx] = *(const f32x4*)&U[(size_t)(l0 + li) * D + idx];
    }
    A_GLOAD(0);
    B_GLOAD(0);
    SB();
    asm volatile("s_waitcnt vmcnt(0) lgkmcnt(0)" ::: "memory");
    SB();
    BAR();

#pragma unroll
    for (int t = 0; t < NT; ++t) {
        const int c = t & 1;

        // ph0: ks0 reads + next-tile staging issue (lands after tile-end barrier)
        UF_READ(t);
        DSREAD_A(c, 0); DSREAD_B(c, 0);
        if (t + 1 < NT) { A_GLOAD(t + 1); B_GLOAD(t + 1); }
        SB();
        SCALE(0, 0); MFMA16(acc0);
        SCALE(1, 0); MFMA16(acc1);
        SB();
        // ph1: ks1 reads (same buffer -> no barrier needed between phases)
        DSREAD_A(c, 1); DSREAD_B(c, 1);
        SB();
        SCALE(0, 1); MFMA16(acc0);
        SCALE(1, 1); MFMA16(acc1);
        SB();
        if (t + 1 < NT) {
            // gloads issued ~2 full phases (>1000 cyc) ago -> aged, cheap drain
            asm volatile("s_waitcnt vmcnt(0)" ::: "memory");
            SB();
            BAR();
        }
    }

    // ---- epilogue: C/D layout col=lane&15, row=(lane>>4)*4+r; 2 l-planes
#pragma unroll
    for (int li = 0; li < 2; ++li) {
        float* op = out + (size_t)(b * L + l0 + li) * S * S;
#pragma unroll
        for (int m = 0; m < 4; ++m) {
            const int row0 = i0 + wm * 64 + m * 16 + ((lane >> 4) << 2);
#pragma unroll
            for (int n = 0; n < 4; ++n) {
                const int col = o0 + wn * 64 + n * 16 + (lane & 15);
#pragma unroll
                for (int r = 0; r < 4; ++r)
                    op[(size_t)(row0 + r) * S + col] =
                        li ? acc1[m][n][r] : acc0[m][n][r];
            }
        }
    }

#undef SB
#undef BAR
#undef A_GLOAD
#undef B_GLOAD
#undef DSREAD_A
#undef DSREAD_B
#undef UF_READ
#undef SCALE
#undef MFMA16
}

// ---------------- fallback (proven R1 kernel): used only if ws < 8MB ----------
__global__ __launch_bounds__(256, 2)
void bla_fb(const float* __restrict__ head, const float* __restrict__ dep,
            const float* __restrict__ U, float* __restrict__ out)
{
    constexpr int S = 512, D = 512, L = 32, BM = 128, BN = 128, BK = 64, NT = 8;
    __shared__ short Al[2][BM * BK];
    __shared__ short Bl[2][BN * BK];
    const int tid = threadIdx.x, lane = tid & 63, wid = tid >> 6;
    const int wm = wid >> 1, wn = wid & 1;
    const int swz = (blockIdx.x & 7) * ((int)gridDim.x >> 3) + (blockIdx.x >> 3);
    const int b = swz >> 9, rem = swz & 511;
    const int l = rem >> 4, it = (rem >> 2) & 3, ot = rem & 3;
    const int i0 = it * BM, o0 = ot * BN;
    const int srow = tid >> 3, scol = (tid & 7) * 8, swb = scol * 2;
    const float* hb = head + (size_t)(b * S + i0 + srow) * D + scol;
    const float* db = dep + (size_t)(b * S + o0 + srow) * D + scol;
    const float* ub = U + l * D + scol;
    f32x4 ra[4][2], rb[4][2], ru[2];
#define FSTAGE_LOAD(t) do { const int k0_ = (t) * BK;                              \
        ru[0] = *(const f32x4*)(ub + k0_); ru[1] = *(const f32x4*)(ub + k0_ + 4);  \
        _Pragma("unroll") for (int p_ = 0; p_ < 4; ++p_) {                         \
            ra[p_][0] = *(const f32x4*)(hb + k0_ + p_ * 32 * D);                   \
            ra[p_][1] = *(const f32x4*)(hb + k0_ + p_ * 32 * D + 4);               \
            rb[p_][0] = *(const f32x4*)(db + k0_ + p_ * 32 * D);                   \
            rb[p_][1] = *(const f32x4*)(db + k0_ + p_ * 32 * D + 4); } } while (0)
#define FSTAGE_WRITE(buf) do { _Pragma("unroll") for (int p_ = 0; p_ < 4; ++p_) {  \
            const int row_ = srow + p_ * 32; const int sb_ = swb ^ ((row_ & 7) << 4); \
            bf16x8 av_, bv_;                                                       \
            _Pragma("unroll") for (int q_ = 0; q_ < 2; ++q_)                       \
                _Pragma("unroll") for (int j_ = 0; j_ < 4; ++j_) {                 \
                    av_[q_ * 4 + j_] = bf16r(ra[p_][q_][j_] * ru[q_][j_]);         \
                    bv_[q_ * 4 + j_] = bf16r(rb[p_][q_][j_]); }                    \
            *(bf16x8*)&Al[buf][row_ * BK + (sb_ >> 1)] = av_;                      \
            *(bf16x8*)&Bl[buf][row_ * BK + (sb_ >> 1)] = bv_; } } while (0)
    f32x4 acc[4][4] = {};
    const int cbase = (lane >> 4) << 4, rsw = (lane & 7) << 4;
#define FCOMPUTE(buf) do { _Pragma("unroll") for (int ks_ = 0; ks_ < 2; ++ks_) {   \
            const int sb2_ = (ks_ * 64 + cbase) ^ rsw; bf16x8 af_[4], bfr_[4];     \
            _Pragma("unroll") for (int f_ = 0; f_ < 4; ++f_) {                     \
                af_[f_] = *(const bf16x8*)&Al[buf][(wm * 64 + f_ * 16 + (lane & 15)) * BK + (sb2_ >> 1)]; \
                bfr_[f_] = *(const bf16x8*)&Bl[buf][(wn * 64 + f_ * 16 + (lane & 15)) * BK + (sb2_ >> 1)]; } \
            _Pragma("unroll") for (int fm_ = 0; fm_ < 4; ++fm_)                    \
                _Pragma("unroll") for (int fn_ = 0; fn_ < 4; ++fn_)                \
                    acc[fm_][fn_] = __builtin_amdgcn_mfma_f32_16x16x32_bf16(       \
                        af_[fm_], bfr_[fn_], acc[fm_][fn_], 0, 0, 0); } } while (0)
    FSTAGE_LOAD(0); FSTAGE_WRITE(0); __syncthreads();
    int cur = 0;
#pragma unroll
    for (int t = 0; t < NT; ++t) {
        if (t + 1 < NT) FSTAGE_LOAD(t + 1);
        FCOMPUTE(cur);
        if (t + 1 < NT) FSTAGE_WRITE(cur ^ 1);
        __syncthreads();
        cur ^= 1;
    }
    float* op = out + (size_t)(b * L + l) * S * S;
#pragma unroll
    for (int fm = 0; fm < 4; ++fm) {
        const int row0 = i0 + wm * 64 + fm * 16 + ((lane >> 4) << 2);
#pragma unroll
        for (int fn = 0; fn < 4; ++fn) {
            const int col = o0 + wn * 64 + fn * 16 + (lane & 15);
#pragma unroll
            for (int r = 0; r < 4; ++r)
                op[(size_t)(row0 + r) * S + col] = acc[fm][fn][r];
        }
    }
#undef FSTAGE_LOAD
#undef FSTAGE_WRITE
#undef FCOMPUTE
}

extern "C" void kernel_launch(void* const* d_in, const int* in_sizes, int n_in,
                              void* d_out, int out_size, void* d_ws, size_t ws_size,
                              hipStream_t stream)
{
    const float* head = (const float*)d_in[0];
    const float* dep  = (const float*)d_in[1];
    const float* U    = (const float*)d_in[2];
    float* out        = (float*)d_out;

    const size_t nelem = (size_t)8 * 512 * 512;
    const size_t need  = nelem * 2 * 2;   // 8MB
    if (ws_size >= need) {
        short* headb = (short*)d_ws;
        short* depb  = headb + nelem;
        cvt_kernel<<<dim3(2048), dim3(256), 0, stream>>>(head, dep, headb, depb);
        bla_gemm8<<<dim3(2048), dim3(256), 0, stream>>>(headb, depb, U, out);
    } else {
        bla_fb<<<dim3(4096), dim3(256), 0, stream>>>(head, dep, U, out);
    }
}